// Round 9
// baseline (392.364 us; speedup 1.0000x reference)
//
#include <hip/hip_runtime.h>

// LinearAttentionBlock: B=8 T=512 FIN=256 D=128
// out   [B,T,D]    @ d_out + 0
// S_out [B,T,D*D]  @ d_out + 524288      (256 MiB -> HBM-write bound floor ~43us)
// Z     [B,T,D]    @ d_out + 524288 + 67108864
//
// Round-9 = round-7/8 resubmit (two container infra failures; kernel never ran).
// S_out stream SPLIT across two launches so the 43us write floor overlaps
// compute on both sides:
//   prefix  : scans all 8 chunks, NT-streams S_out for chunks 0..3 (134 MB)
//   mega    : attn(+FFN) blocks + s_write roles for chunks 4..7 (134 MB)
// Both write paths are bit-exact ports of previously verified kernels.
// (Round-4 note: cooperative grid.sync mega-fusion corrupted S_out -> off the table.)

constexpr int BB = 8, TT = 512, FIN_ = 256, DD = 128;
constexpr int NROW = BB * TT;       // 4096
constexpr int CLEN = 64, NCH = 8;   // chunk length, chunks per batch
constexpr int WSPLIT = 4;           // chunks 0..WSPLIT-1 written by prefix, rest by mega
constexpr float CLAMPV = 1e20f;

typedef float f4v __attribute__((ext_vector_type(4)));
typedef float f2v __attribute__((ext_vector_type(2)));

// ---------------- 1. LN fused into xn @ {Wk,Wq,Wv,Ws} GEMM, 64x64 tiles, dbuf ----------------
__global__ __launch_bounds__(256) void gemm_qkvs(
    const float* __restrict__ x,
    const float* __restrict__ gamma, const float* __restrict__ beta,
    const float* __restrict__ Wk, const float* __restrict__ Wq,
    const float* __restrict__ Wv, const float* __restrict__ Ws,
    const float* __restrict__ bs,
    float* __restrict__ Kb, float* __restrict__ Qb,
    float* __restrict__ Vb, float* __restrict__ Rb)
{
  int ct = blockIdx.x, rt = blockIdx.y;
  int mat = ct >> 1, cb = (ct & 1) * 64;
  const float* W = (mat == 0) ? Wk : (mat == 1) ? Wq : (mat == 2) ? Wv : Ws;
  float* Ob      = (mat == 0) ? Kb : (mat == 1) ? Qb : (mat == 2) ? Vb : Rb;
  __shared__ float As[2][16][64];   // [buf][k][m]
  __shared__ float Bs[2][16][64];   // [buf][k][n]
  __shared__ float mu_s[64], rs_s[64];
  int tid = threadIdx.x;
  // ---- LN stats: 4 lanes per row ----
  {
    int row = tid >> 2, q = tid & 3;
    const float* xr = &x[(rt * 64 + row) * FIN_ + q * 64];
    float sum = 0.f, sq = 0.f;
#pragma unroll
    for (int u = 0; u < 16; u++) {
      float4 v = *(const float4*)&xr[u * 4];
      sum += v.x + v.y + v.z + v.w;
      sq  += v.x * v.x + v.y * v.y + v.z * v.z + v.w * v.w;
    }
    sum += __shfl_xor(sum, 1); sq += __shfl_xor(sq, 1);
    sum += __shfl_xor(sum, 2); sq += __shfl_xor(sq, 2);
    if (q == 0) {
      float mu = sum * (1.0f / FIN_);
      float var = sq * (1.0f / FIN_) - mu * mu;
      mu_s[row] = mu;
      rs_s[row] = rsqrtf(var + 1e-5f);
    }
  }
  __syncthreads();
  int tn = tid & 15, tm = tid >> 4;
  int lm = tid >> 2, lq = tid & 3;
  int lk = tid >> 4, ln4 = (tid & 15) * 4;
  float acc[4][4] = {};
  float mu = mu_s[lm], rs = rs_s[lm];
  float4 xa = *(const float4*)&x[(rt * 64 + lm) * FIN_ + lq * 4];
  float4 ga = *(const float4*)&gamma[lq * 4];
  float4 be = *(const float4*)&beta[lq * 4];
  float4 wb = *(const float4*)&W[lk * DD + cb + ln4];
  int cur = 0;
  for (int k0 = 0; k0 < FIN_; k0 += 16) {
    As[cur][lq * 4 + 0][lm] = (xa.x - mu) * rs * ga.x + be.x;
    As[cur][lq * 4 + 1][lm] = (xa.y - mu) * rs * ga.y + be.y;
    As[cur][lq * 4 + 2][lm] = (xa.z - mu) * rs * ga.z + be.z;
    As[cur][lq * 4 + 3][lm] = (xa.w - mu) * rs * ga.w + be.w;
    *(float4*)&Bs[cur][lk][ln4] = wb;
    if (k0 + 16 < FIN_) {
      xa = *(const float4*)&x[(rt * 64 + lm) * FIN_ + k0 + 16 + lq * 4];
      ga = *(const float4*)&gamma[k0 + 16 + lq * 4];
      be = *(const float4*)&beta[k0 + 16 + lq * 4];
      wb = *(const float4*)&W[(k0 + 16 + lk) * DD + cb + ln4];
    }
    __syncthreads();
#pragma unroll
    for (int k = 0; k < 16; k++) {
      float4 a = *(const float4*)&As[cur][k][tm * 4];
      float4 b = *(const float4*)&Bs[cur][k][tn * 4];
      float ar[4] = {a.x, a.y, a.z, a.w};
      float br[4] = {b.x, b.y, b.z, b.w};
#pragma unroll
      for (int i = 0; i < 4; i++)
#pragma unroll
        for (int j = 0; j < 4; j++) acc[i][j] += ar[i] * br[j];
    }
    cur ^= 1;
  }
#pragma unroll
  for (int i = 0; i < 4; i++) {
    int row = rt * 64 + tm * 4 + i;
    int col = cb + tn * 4;
    float vals[4];
#pragma unroll
    for (int j = 0; j < 4; j++) {
      float v = acc[i][j];
      if (mat <= 1) v = (v > 0.f) ? v + 1.f : expf(v);   // phi = elu + 1
      else if (mat == 3) v += bs[col + j];
      vals[j] = v;
    }
    *(float4*)&Ob[row * DD + col] = make_float4(vals[0], vals[1], vals[2], vals[3]);
  }
}

// ---------------- 2. prefix scan + S_out stream for chunks 0..WSPLIT-1 ----------------
// grid (2 jh, 16 it, BB). Block owns 8 i-rows x 64 j-cols. acc chain (prefS) is
// continuous; accW restarts per chunk -> S_out[t] = pref + accW (bit-exact round-6 path).
__global__ __launch_bounds__(256) void prefix_kernel(
    const float* __restrict__ Kb, const float* __restrict__ Vb,
    const float* __restrict__ S0, const float* __restrict__ Z0,
    float* __restrict__ prefS, float* __restrict__ prefz,
    float* __restrict__ Sout)
{
  int jh = blockIdx.x, it = blockIdx.y, b = blockIdx.z;
  int i0 = it * 8, j0 = jh * 64;
  __shared__ float Ks[2][CLEN][8];    //  4 KB
  __shared__ float Vs[2][CLEN][64];   // 32 KB
  int tid = threadIdx.x;
  int il = tid >> 5, jl = tid & 31;   // row i0+il, cols j0+2jl, +1
  float2 s0v = *(const float2*)&S0[b * DD * DD + (i0 + il) * DD + j0 + jl * 2];
  float acc0 = 0.f, acc1 = 0.f, zacc = 0.f;
  float z0v = (jh == 0 && tid < 8) ? Z0[b * DD + i0 + tid] : 0.f;
  // stage chunk 0 into buf 0
  {
    const float* Kc = Kb + (b * TT) * DD;
    const float* Vc = Vb + (b * TT) * DD;
    int t = tid >> 2, i2 = (tid & 3) * 2;
    *(float2*)&Ks[0][t][i2] = *(const float2*)&Kc[t * DD + i0 + i2];
#pragma unroll
    for (int u = 0; u < 4; u++) {
      int idx = u * 256 + tid;
      int tv = idx >> 4, j4 = (idx & 15) * 4;
      *(float4*)&Vs[0][tv][j4] = *(const float4*)&Vc[tv * DD + j0 + j4];
    }
  }
  int cur = 0;
  for (int c = 0; c < NCH; c++) {
    __syncthreads();                  // buf[cur] staged
    float2 kq;
    float4 vq[4];
    if (c + 1 < NCH) {                // prefetch next chunk to regs
      const float* Kc = Kb + (b * TT + (c + 1) * CLEN) * DD;
      const float* Vc = Vb + (b * TT + (c + 1) * CLEN) * DD;
      kq = *(const float2*)&Kc[(tid >> 2) * DD + i0 + (tid & 3) * 2];
#pragma unroll
      for (int u = 0; u < 4; u++) {
        int idx = u * 256 + tid;
        vq[u] = *(const float4*)&Vc[(idx >> 4) * DD + j0 + (idx & 15) * 4];
      }
    }
    // exclusive prefix out (cached: consumed by attn/mega next launch)
    float p0 = acc0 + s0v.x, p1 = acc1 + s0v.y;
    *(float2*)&prefS[(size_t)(b * NCH + c) * DD * DD + (i0 + il) * DD + j0 + jl * 2] =
        make_float2(p0, p1);
    if (jh == 0 && tid < 8)
      prefz[(b * NCH + c) * DD + i0 + tid] = zacc + z0v;
    if (c < WSPLIT) {
      // scan + S_out stream (bit-exact round-6 path)
      float w0 = 0.f, w1 = 0.f;
      float* So = Sout + (size_t)(b * TT + c * CLEN) * (DD * DD) + (i0 + il) * DD + j0 + jl * 2;
#pragma unroll 4
      for (int t = 0; t < CLEN; t++) {
        float k = Ks[cur][t][il];
        float2 v2 = *(const float2*)&Vs[cur][t][jl * 2];
        acc0 += k * v2.x; acc1 += k * v2.y;
        w0 += k * v2.x;   w1 += k * v2.y;
        f2v o2;
        o2.x = fminf(fmaxf(p0 + w0, -CLAMPV), CLAMPV);
        o2.y = fminf(fmaxf(p1 + w1, -CLAMPV), CLAMPV);
        __builtin_nontemporal_store(o2, (f2v*)&So[(size_t)t * (DD * DD)]);
      }
    } else {
      // lean accumulate-only scan (S_out for these chunks written by mega)
#pragma unroll 8
      for (int t = 0; t < CLEN; t++) {
        float k = Ks[cur][t][il];
        float2 v2 = *(const float2*)&Vs[cur][t][jl * 2];
        acc0 += k * v2.x; acc1 += k * v2.y;
      }
    }
    if (jh == 0 && tid < 8) {
      float z = 0.f;
#pragma unroll 8
      for (int t = 0; t < CLEN; t++) z += Ks[cur][t][tid];
      zacc += z;
    }
    if (c + 1 < NCH) {                // write prefetched regs into other buffer
      *(float2*)&Ks[cur ^ 1][tid >> 2][(tid & 3) * 2] = kq;
#pragma unroll
      for (int u = 0; u < 4; u++) {
        int idx = u * 256 + tid;
        *(float4*)&Vs[cur ^ 1][idx >> 4][(idx & 15) * 4] = vq[u];
      }
    }
    cur ^= 1;
  }
}

// ---------------- 3. MEGA: attn(+FFN) + s_write roles for chunks WSPLIT..7 ----------------
// grid (16, NCH, BB): x<8 -> attn role (sub=x); x>=8 -> s_write role (it=x-8, 16 rows,
// active only for c>=WSPLIT; else immediate exit). s_write code = round-5 verified path.
union MegaSmem {
  struct {
    float KsT[DD][CLEN + 2];   // 33792 B
    float Qs[8][132];          //  4224 B
    float sc[8][CLEN + 2];     //  2112 B
    float zeff[DD];            //   512 B
    float den[8];              //    32 B
    float Ao[8][132];          //  4224 B
    float H1[8][132];          //  4224 B
  } a;                         // 49120 B
  struct {
    float Vs[CLEN][DD];        // 32768 B
    float Ksm[CLEN][16];       //  4096 B
  } s;
};

__global__ __launch_bounds__(256) void mega_kernel(
    const float* __restrict__ Kb, const float* __restrict__ Qb,
    const float* __restrict__ Vb, const float* __restrict__ prefS,
    const float* __restrict__ prefz, const float* __restrict__ Rb,
    const float* __restrict__ W1, const float* __restrict__ b1,
    const float* __restrict__ W2, const float* __restrict__ b2,
    float* __restrict__ Zout, float* __restrict__ out_main,
    float* __restrict__ Sout)
{
  __shared__ MegaSmem sm;
  int c = blockIdx.y, b = blockIdx.z, tid = threadIdx.x;
  const float* Kc = Kb + (b * TT + c * CLEN) * DD;
  const float* Vc = Vb + (b * TT + c * CLEN) * DD;

  if (blockIdx.x >= 8) {
    if (c < WSPLIT) return;           // these chunks written by prefix
    // ---------------- s_write role: 16 state rows, NT-stream ----------------
    int i0 = (blockIdx.x - 8) * 16;
#pragma unroll
    for (int u = 0; u < 8; u++) {
      int idx = u * 256 + tid;
      int t = idx >> 5, c4 = (idx & 31) * 4;
      *(float4*)&sm.s.Vs[t][c4] = *(const float4*)&Vc[t * DD + c4];
    }
#pragma unroll
    for (int u = 0; u < 4; u++) {
      int idx = u * 256 + tid;
      int t = idx >> 4, r = idx & 15;
      sm.s.Ksm[t][r] = Kc[t * DD + i0 + r];
    }
    __syncthreads();
    int irow = tid >> 5, jq = tid & 31;
    int j = jq * 4;
    size_t pbase = (size_t)(b * NCH + c) * DD * DD;
    float4 prefA = *(const float4*)&prefS[pbase + (i0 + irow) * DD + j];
    float4 prefB = *(const float4*)&prefS[pbase + (i0 + 8 + irow) * DD + j];
    float4 accA = make_float4(0.f, 0.f, 0.f, 0.f);
    float4 accB = make_float4(0.f, 0.f, 0.f, 0.f);
    float* SoA = Sout + (size_t)(b * TT + c * CLEN) * (DD * DD) + (i0 + irow) * DD + j;
    float* SoB = SoA + 8 * DD;
#pragma unroll 2
    for (int t = 0; t < CLEN; t++) {
      float4 v4 = *(const float4*)&sm.s.Vs[t][j];
      float kA = sm.s.Ksm[t][irow];
      float kB = sm.s.Ksm[t][irow + 8];
      accA.x += kA * v4.x; accA.y += kA * v4.y;
      accA.z += kA * v4.z; accA.w += kA * v4.w;
      f4v oA;
      oA.x = fminf(fmaxf(prefA.x + accA.x, -CLAMPV), CLAMPV);
      oA.y = fminf(fmaxf(prefA.y + accA.y, -CLAMPV), CLAMPV);
      oA.z = fminf(fmaxf(prefA.z + accA.z, -CLAMPV), CLAMPV);
      oA.w = fminf(fmaxf(prefA.w + accA.w, -CLAMPV), CLAMPV);
      __builtin_nontemporal_store(oA, (f4v*)&SoA[(size_t)t * (DD * DD)]);
      accB.x += kB * v4.x; accB.y += kB * v4.y;
      accB.z += kB * v4.z; accB.w += kB * v4.w;
      f4v oB;
      oB.x = fminf(fmaxf(prefB.x + accB.x, -CLAMPV), CLAMPV);
      oB.y = fminf(fmaxf(prefB.y + accB.y, -CLAMPV), CLAMPV);
      oB.z = fminf(fmaxf(prefB.z + accB.z, -CLAMPV), CLAMPV);
      oB.w = fminf(fmaxf(prefB.w + accB.w, -CLAMPV), CLAMPV);
      __builtin_nontemporal_store(oB, (f4v*)&SoB[(size_t)t * (DD * DD)]);
    }
    return;
  }

  // ---------------- attn + FFN role: 8 t-rows ----------------
  int sub = blockIdx.x;
  int t0 = sub * 8;
  int tlim = t0 + 8;
  const float* Qc = Qb + (b * TT + c * CLEN) * DD;
  for (int idx = tid; idx < tlim * 32; idx += 256) {
    int t = idx >> 5, c4 = (idx & 31) * 4;
    float4 vv = *(const float4*)&Kc[t * DD + c4];
    sm.a.KsT[c4 + 0][t] = vv.x; sm.a.KsT[c4 + 1][t] = vv.y;
    sm.a.KsT[c4 + 2][t] = vv.z; sm.a.KsT[c4 + 3][t] = vv.w;
  }
  {
    int r = tid >> 5, c4 = (tid & 31) * 4;
    *(float4*)&sm.a.Qs[r][c4] = *(const float4*)&Qc[(t0 + r) * DD + c4];
  }
  if (tid < DD) sm.a.zeff[tid] = prefz[(b * NCH + c) * DD + tid];
  __syncthreads();
  // scores
  {
    int tm = tid >> 5, tn = tid & 31;
    int tau0 = tn * 2;
    if (tau0 < tlim) {
      float s0 = 0.f, s1 = 0.f;
#pragma unroll 8
      for (int k = 0; k < DD; k++) {
        float q = sm.a.Qs[tm][k];
        float2 kk = *(const float2*)&sm.a.KsT[k][tau0];
        s0 += q * kk.x;
        s1 += q * kk.y;
      }
      int t = t0 + tm;
      sm.a.sc[tm][tau0]     = (tau0     <= t) ? s0 : 0.f;
      sm.a.sc[tm][tau0 + 1] = (tau0 + 1 <= t) ? s1 : 0.f;
    }
  }
  __syncthreads();
  // den: 32 lanes per row, shuffle-reduce
  {
    int r = tid >> 5, g = tid & 31;
    int t = t0 + r;
    float p = 0.f;
    for (int tau = g; tau <= t; tau += 32) p += sm.a.sc[r][tau];
#pragma unroll 4
    for (int k = g; k < DD; k += 32) p += sm.a.Qs[r][k] * sm.a.zeff[k];
#pragma unroll
    for (int off = 1; off < 32; off <<= 1) p += __shfl_xor(p, off);
    if (g == 0) sm.a.den[r] = p + 1e-5f;
  }
  __syncthreads();
  // numerator -> Ao (LDS)
  int tl = tid & 31, r = tid >> 5;
  int l0 = tl * 4;
  {
    float n0[4] = {};
#pragma unroll 4
    for (int tau = 0; tau < tlim; tau++) {
      float4 v4 = *(const float4*)&Vc[tau * DD + l0];
      float s = sm.a.sc[r][tau];
      n0[0] += s * v4.x; n0[1] += s * v4.y; n0[2] += s * v4.z; n0[3] += s * v4.w;
    }
    const float* P = prefS + (size_t)(b * NCH + c) * DD * DD;
#pragma unroll 4
    for (int i = 0; i < DD; i++) {
      float4 p4 = *(const float4*)&P[i * DD + l0];
      float q = sm.a.Qs[r][i];
      n0[0] += q * p4.x; n0[1] += q * p4.y; n0[2] += q * p4.z; n0[3] += q * p4.w;
    }
    float dd = sm.a.den[r];
    *(float4*)&sm.a.Ao[r][l0] = make_float4(n0[0] / dd, n0[1] / dd, n0[2] / dd, n0[3] / dd);
  }
  // Z output: sub==7 has full K staged
  if (sub == 7 && tid < DD) {
    int i = tid;
    float a = sm.a.zeff[i];
    for (int t = 0; t < CLEN; t++) {
      a += sm.a.KsT[i][t];
      a = fminf(fmaxf(a, -CLAMPV), CLAMPV);
      __builtin_nontemporal_store(a, &Zout[(size_t)(b * TT + c * CLEN + t) * DD + i]);
    }
  }
  __syncthreads();
  // FFN layer 1
  {
    float a1[4] = {};
#pragma unroll 8
    for (int k = 0; k < DD; k++) {
      float4 w = *(const float4*)&W1[k * DD + l0];
      float a = sm.a.Ao[r][k];
      a1[0] += a * w.x; a1[1] += a * w.y; a1[2] += a * w.z; a1[3] += a * w.w;
    }
    float4 bv = *(const float4*)&b1[l0];
    float4 h;
    h.x = fmaxf(a1[0] + bv.x, 0.f);
    h.y = fmaxf(a1[1] + bv.y, 0.f);
    h.z = fmaxf(a1[2] + bv.z, 0.f);
    h.w = fmaxf(a1[3] + bv.w, 0.f);
    *(float4*)&sm.a.H1[r][l0] = h;
  }
  __syncthreads();
  // FFN layer 2 + residual
  {
    float a2[4] = {};
#pragma unroll 8
    for (int k = 0; k < DD; k++) {
      float4 w = *(const float4*)&W2[k * DD + l0];
      float a = sm.a.H1[r][k];
      a2[0] += a * w.x; a2[1] += a * w.y; a2[2] += a * w.z; a2[3] += a * w.w;
    }
    int grow = b * TT + c * CLEN + t0 + r;
    float4 b2v = *(const float4*)&b2[l0];
    float4 rv = *(const float4*)&Rb[grow * DD + l0];
    float4 o;
    o.x = fmaxf(a2[0] + b2v.x, 0.f) + rv.x;
    o.y = fmaxf(a2[1] + b2v.y, 0.f) + rv.y;
    o.z = fmaxf(a2[2] + b2v.z, 0.f) + rv.z;
    o.w = fmaxf(a2[3] + b2v.w, 0.f) + rv.w;
    *(float4*)&out_main[grow * DD + l0] = o;
  }
}

extern "C" void kernel_launch(void* const* d_in, const int* in_sizes, int n_in,
                              void* d_out, int out_size, void* d_ws, size_t ws_size,
                              hipStream_t stream)
{
  const float* x     = (const float*)d_in[0];
  const float* S0    = (const float*)d_in[1];
  const float* Z0    = (const float*)d_in[2];
  const float* gamma = (const float*)d_in[3];
  const float* beta  = (const float*)d_in[4];
  const float* Wk    = (const float*)d_in[5];
  const float* Wq    = (const float*)d_in[6];
  const float* Wv    = (const float*)d_in[7];
  const float* W1    = (const float*)d_in[8];
  const float* b1    = (const float*)d_in[9];
  const float* W2    = (const float*)d_in[10];
  const float* b2    = (const float*)d_in[11];
  const float* Ws    = (const float*)d_in[12];
  const float* bs    = (const float*)d_in[13];

  float* out_main = (float*)d_out;                       // [B,T,D]
  float* Sout = out_main + NROW * DD;                    // [B,T,D*D]
  float* Zout = Sout + (size_t)NROW * DD * DD;           // [B,T,D]

  float* ws_f   = (float*)d_ws;
  float* Kb     = ws_f;                  // 524288
  float* Qb     = Kb + 524288;           // 524288
  float* Vb     = Qb + 524288;           // 524288
  float* Rb     = Vb + 524288;           // 524288  (xn@Ws + bs)
  float* prefS  = Rb + 524288;           // 1048576 (exclusive prefix + S0)
  float* prefz  = prefS + 1048576;       // 8192    (exclusive prefix + Z0)

  gemm_qkvs<<<dim3(8, 64), 256, 0, stream>>>(x, gamma, beta, Wk, Wq, Wv, Ws, bs,
                                             Kb, Qb, Vb, Rb);
  prefix_kernel<<<dim3(2, 16, BB), 256, 0, stream>>>(Kb, Vb, S0, Z0, prefS, prefz, Sout);
  mega_kernel<<<dim3(16, NCH, BB), 256, 0, stream>>>(Kb, Qb, Vb, prefS, prefz, Rb,
                                                     W1, b1, W2, b2,
                                                     Zout, out_main, Sout);
}

// Round 10
// 363.938 us; speedup vs baseline: 1.0781x; 1.0781x over previous
//
#include <hip/hip_runtime.h>

// LinearAttentionBlock: B=8 T=512 FIN=256 D=128
// out   [B,T,D]    @ d_out + 0
// S_out [B,T,D*D]  @ d_out + 524288      (256 MiB -> HBM-write bound floor ~43us)
// Z     [B,T,D]    @ d_out + 524288 + 67108864
//
// Round-10 = exact revert to the round-6 verified kernel (364.5 us, absmax 2.0).
// Round-9 post-mortem: splitting the S_out stream across prefix+mega launches
// REGRESSED (392 us) — fragmenting a BW-bound NT stream forfeits single-launch
// write-pipe saturation. Keep ALL S_out emission fused into the prefix scan.
// (Round-4 note: cooperative grid.sync mega-fusion corrupted S_out -> off the table.)

constexpr int BB = 8, TT = 512, FIN_ = 256, DD = 128;
constexpr int NROW = BB * TT;       // 4096
constexpr int CLEN = 64, NCH = 8;   // chunk length, chunks per batch
constexpr float CLAMPV = 1e20f;

typedef float f4v __attribute__((ext_vector_type(4)));
typedef float f2v __attribute__((ext_vector_type(2)));

// ---------------- 1. LN fused into xn @ {Wk,Wq,Wv,Ws} GEMM, 64x64 tiles, dbuf ----------------
__global__ __launch_bounds__(256) void gemm_qkvs(
    const float* __restrict__ x,
    const float* __restrict__ gamma, const float* __restrict__ beta,
    const float* __restrict__ Wk, const float* __restrict__ Wq,
    const float* __restrict__ Wv, const float* __restrict__ Ws,
    const float* __restrict__ bs,
    float* __restrict__ Kb, float* __restrict__ Qb,
    float* __restrict__ Vb, float* __restrict__ Rb)
{
  int ct = blockIdx.x, rt = blockIdx.y;
  int mat = ct >> 1, cb = (ct & 1) * 64;
  const float* W = (mat == 0) ? Wk : (mat == 1) ? Wq : (mat == 2) ? Wv : Ws;
  float* Ob      = (mat == 0) ? Kb : (mat == 1) ? Qb : (mat == 2) ? Vb : Rb;
  __shared__ float As[2][16][64];   // [buf][k][m]
  __shared__ float Bs[2][16][64];   // [buf][k][n]
  __shared__ float mu_s[64], rs_s[64];
  int tid = threadIdx.x;
  // ---- LN stats: 4 lanes per row ----
  {
    int row = tid >> 2, q = tid & 3;
    const float* xr = &x[(rt * 64 + row) * FIN_ + q * 64];
    float sum = 0.f, sq = 0.f;
#pragma unroll
    for (int u = 0; u < 16; u++) {
      float4 v = *(const float4*)&xr[u * 4];
      sum += v.x + v.y + v.z + v.w;
      sq  += v.x * v.x + v.y * v.y + v.z * v.z + v.w * v.w;
    }
    sum += __shfl_xor(sum, 1); sq += __shfl_xor(sq, 1);
    sum += __shfl_xor(sum, 2); sq += __shfl_xor(sq, 2);
    if (q == 0) {
      float mu = sum * (1.0f / FIN_);
      float var = sq * (1.0f / FIN_) - mu * mu;
      mu_s[row] = mu;
      rs_s[row] = rsqrtf(var + 1e-5f);
    }
  }
  __syncthreads();
  int tn = tid & 15, tm = tid >> 4;
  int lm = tid >> 2, lq = tid & 3;
  int lk = tid >> 4, ln4 = (tid & 15) * 4;
  float acc[4][4] = {};
  float mu = mu_s[lm], rs = rs_s[lm];
  float4 xa = *(const float4*)&x[(rt * 64 + lm) * FIN_ + lq * 4];
  float4 ga = *(const float4*)&gamma[lq * 4];
  float4 be = *(const float4*)&beta[lq * 4];
  float4 wb = *(const float4*)&W[lk * DD + cb + ln4];
  int cur = 0;
  for (int k0 = 0; k0 < FIN_; k0 += 16) {
    As[cur][lq * 4 + 0][lm] = (xa.x - mu) * rs * ga.x + be.x;
    As[cur][lq * 4 + 1][lm] = (xa.y - mu) * rs * ga.y + be.y;
    As[cur][lq * 4 + 2][lm] = (xa.z - mu) * rs * ga.z + be.z;
    As[cur][lq * 4 + 3][lm] = (xa.w - mu) * rs * ga.w + be.w;
    *(float4*)&Bs[cur][lk][ln4] = wb;
    if (k0 + 16 < FIN_) {
      xa = *(const float4*)&x[(rt * 64 + lm) * FIN_ + k0 + 16 + lq * 4];
      ga = *(const float4*)&gamma[k0 + 16 + lq * 4];
      be = *(const float4*)&beta[k0 + 16 + lq * 4];
      wb = *(const float4*)&W[(k0 + 16 + lk) * DD + cb + ln4];
    }
    __syncthreads();
#pragma unroll
    for (int k = 0; k < 16; k++) {
      float4 a = *(const float4*)&As[cur][k][tm * 4];
      float4 b = *(const float4*)&Bs[cur][k][tn * 4];
      float ar[4] = {a.x, a.y, a.z, a.w};
      float br[4] = {b.x, b.y, b.z, b.w};
#pragma unroll
      for (int i = 0; i < 4; i++)
#pragma unroll
        for (int j = 0; j < 4; j++) acc[i][j] += ar[i] * br[j];
    }
    cur ^= 1;
  }
#pragma unroll
  for (int i = 0; i < 4; i++) {
    int row = rt * 64 + tm * 4 + i;
    int col = cb + tn * 4;
    float vals[4];
#pragma unroll
    for (int j = 0; j < 4; j++) {
      float v = acc[i][j];
      if (mat <= 1) v = (v > 0.f) ? v + 1.f : expf(v);   // phi = elu + 1
      else if (mat == 3) v += bs[col + j];
      vals[j] = v;
    }
    *(float4*)&Ob[row * DD + col] = make_float4(vals[0], vals[1], vals[2], vals[3]);
  }
}

// ---------------- 2. prefix scan + fused S_out stream: grid (2 jh, 16 it, BB) ----------------
// Block owns 8 i-rows x 64 j-cols. Per chunk: write exclusive prefix (prefS), then scan
// t=0..63 keeping TWO accumulators: acc (continuous chain -> prefS, order preserved) and
// accW (restarts per chunk -> S_out[t] = pref + accW, bit-identical to the old s_write).
// S_out is NT-streamed (write-once 268 MB); 256B contiguous segments per wave row.
__global__ __launch_bounds__(256) void prefix_kernel(
    const float* __restrict__ Kb, const float* __restrict__ Vb,
    const float* __restrict__ S0, const float* __restrict__ Z0,
    float* __restrict__ prefS, float* __restrict__ prefz,
    float* __restrict__ Sout)
{
  int jh = blockIdx.x, it = blockIdx.y, b = blockIdx.z;
  int i0 = it * 8, j0 = jh * 64;
  __shared__ float Ks[2][CLEN][8];    //  4 KB
  __shared__ float Vs[2][CLEN][64];   // 32 KB
  int tid = threadIdx.x;
  int il = tid >> 5, jl = tid & 31;   // row i0+il, cols j0+2jl, +1
  float2 s0v = *(const float2*)&S0[b * DD * DD + (i0 + il) * DD + j0 + jl * 2];
  float acc0 = 0.f, acc1 = 0.f, zacc = 0.f;
  float z0v = (jh == 0 && tid < 8) ? Z0[b * DD + i0 + tid] : 0.f;
  // stage chunk 0 into buf 0
  {
    const float* Kc = Kb + (b * TT) * DD;
    const float* Vc = Vb + (b * TT) * DD;
    int t = tid >> 2, i2 = (tid & 3) * 2;
    *(float2*)&Ks[0][t][i2] = *(const float2*)&Kc[t * DD + i0 + i2];
#pragma unroll
    for (int u = 0; u < 4; u++) {
      int idx = u * 256 + tid;
      int tv = idx >> 4, j4 = (idx & 15) * 4;
      *(float4*)&Vs[0][tv][j4] = *(const float4*)&Vc[tv * DD + j0 + j4];
    }
  }
  int cur = 0;
  for (int c = 0; c < NCH; c++) {
    __syncthreads();                  // buf[cur] staged
    float2 kq;
    float4 vq[4];
    if (c + 1 < NCH) {                // prefetch next chunk to regs
      const float* Kc = Kb + (b * TT + (c + 1) * CLEN) * DD;
      const float* Vc = Vb + (b * TT + (c + 1) * CLEN) * DD;
      kq = *(const float2*)&Kc[(tid >> 2) * DD + i0 + (tid & 3) * 2];
#pragma unroll
      for (int u = 0; u < 4; u++) {
        int idx = u * 256 + tid;
        vq[u] = *(const float4*)&Vc[(idx >> 4) * DD + j0 + (idx & 15) * 4];
      }
    }
    // exclusive prefix out (cached: consumed by attn next launch)
    float p0 = acc0 + s0v.x, p1 = acc1 + s0v.y;
    *(float2*)&prefS[(size_t)(b * NCH + c) * DD * DD + (i0 + il) * DD + j0 + jl * 2] =
        make_float2(p0, p1);
    if (jh == 0 && tid < 8)
      prefz[(b * NCH + c) * DD + i0 + tid] = zacc + z0v;
    // scan chunk: acc chain (prefS semantics) + accW (S_out within-chunk cumsum)
    float w0 = 0.f, w1 = 0.f;
    float* So = Sout + (size_t)(b * TT + c * CLEN) * (DD * DD) + (i0 + il) * DD + j0 + jl * 2;
#pragma unroll 4
    for (int t = 0; t < CLEN; t++) {
      float k = Ks[cur][t][il];
      float2 v2 = *(const float2*)&Vs[cur][t][jl * 2];
      acc0 += k * v2.x; acc1 += k * v2.y;
      w0 += k * v2.x;   w1 += k * v2.y;
      f2v o2;
      o2.x = fminf(fmaxf(p0 + w0, -CLAMPV), CLAMPV);
      o2.y = fminf(fmaxf(p1 + w1, -CLAMPV), CLAMPV);
      __builtin_nontemporal_store(o2, (f2v*)&So[(size_t)t * (DD * DD)]);
    }
    if (jh == 0 && tid < 8) {
      float z = 0.f;
#pragma unroll 8
      for (int t = 0; t < CLEN; t++) z += Ks[cur][t][tid];
      zacc += z;
    }
    if (c + 1 < NCH) {                // write prefetched regs into other buffer
      *(float2*)&Ks[cur ^ 1][tid >> 2][(tid & 3) * 2] = kq;
#pragma unroll
      for (int u = 0; u < 4; u++) {
        int idx = u * 256 + tid;
        *(float4*)&Vs[cur ^ 1][idx >> 4][(idx & 15) * 4] = vq[u];
      }
    }
    cur ^= 1;
  }
}

// ---------------- 3. attn + FFN: grid (8 sub, NCH, BB) = 512 blocks, 3/CU ----------------
__global__ __launch_bounds__(256) void attn_kernel(
    const float* __restrict__ Kb, const float* __restrict__ Qb,
    const float* __restrict__ Vb, const float* __restrict__ prefS,
    const float* __restrict__ prefz, const float* __restrict__ Rb,
    const float* __restrict__ W1, const float* __restrict__ b1,
    const float* __restrict__ W2, const float* __restrict__ b2,
    float* __restrict__ Zout, float* __restrict__ out_main)
{
  __shared__ float KsT[DD][CLEN + 2];   // 33792 B
  __shared__ float Qs[8][132];          //  4224 B
  __shared__ float sc[8][CLEN + 2];     //  2112 B
  __shared__ float zeff[DD];
  __shared__ float den[8];
  __shared__ float Ao[8][132];          //  4224 B
  __shared__ float H1[8][132];          //  4224 B
  int c = blockIdx.y, b = blockIdx.z, tid = threadIdx.x;
  const float* Kc = Kb + (b * TT + c * CLEN) * DD;
  const float* Vc = Vb + (b * TT + c * CLEN) * DD;
  int sub = blockIdx.x;
  int t0 = sub * 8;
  int tlim = t0 + 8;
  const float* Qc = Qb + (b * TT + c * CLEN) * DD;
  for (int idx = tid; idx < tlim * 32; idx += 256) {
    int t = idx >> 5, c4 = (idx & 31) * 4;
    float4 vv = *(const float4*)&Kc[t * DD + c4];
    KsT[c4 + 0][t] = vv.x; KsT[c4 + 1][t] = vv.y;
    KsT[c4 + 2][t] = vv.z; KsT[c4 + 3][t] = vv.w;
  }
  {
    int r = tid >> 5, c4 = (tid & 31) * 4;
    *(float4*)&Qs[r][c4] = *(const float4*)&Qc[(t0 + r) * DD + c4];
  }
  if (tid < DD) zeff[tid] = prefz[(b * NCH + c) * DD + tid];
  __syncthreads();
  // scores
  {
    int tm = tid >> 5, tn = tid & 31;
    int tau0 = tn * 2;
    if (tau0 < tlim) {
      float s0 = 0.f, s1 = 0.f;
#pragma unroll 8
      for (int k = 0; k < DD; k++) {
        float q = Qs[tm][k];
        float2 kk = *(const float2*)&KsT[k][tau0];
        s0 += q * kk.x;
        s1 += q * kk.y;
      }
      int t = t0 + tm;
      sc[tm][tau0]     = (tau0     <= t) ? s0 : 0.f;
      sc[tm][tau0 + 1] = (tau0 + 1 <= t) ? s1 : 0.f;
    }
  }
  __syncthreads();
  // den: 32 lanes per row, shuffle-reduce
  {
    int r = tid >> 5, g = tid & 31;
    int t = t0 + r;
    float p = 0.f;
    for (int tau = g; tau <= t; tau += 32) p += sc[r][tau];
#pragma unroll 4
    for (int k = g; k < DD; k += 32) p += Qs[r][k] * zeff[k];
#pragma unroll
    for (int off = 1; off < 32; off <<= 1) p += __shfl_xor(p, off);
    if (g == 0) den[r] = p + 1e-5f;
  }
  __syncthreads();
  // numerator -> Ao (LDS)
  int tl = tid & 31, r = tid >> 5;
  int l0 = tl * 4;
  {
    float n0[4] = {};
#pragma unroll 4
    for (int tau = 0; tau < tlim; tau++) {
      float4 v4 = *(const float4*)&Vc[tau * DD + l0];
      float s = sc[r][tau];
      n0[0] += s * v4.x; n0[1] += s * v4.y; n0[2] += s * v4.z; n0[3] += s * v4.w;
    }
    const float* P = prefS + (size_t)(b * NCH + c) * DD * DD;
#pragma unroll 4
    for (int i = 0; i < DD; i++) {
      float4 p4 = *(const float4*)&P[i * DD + l0];
      float q = Qs[r][i];
      n0[0] += q * p4.x; n0[1] += q * p4.y; n0[2] += q * p4.z; n0[3] += q * p4.w;
    }
    float dd = den[r];
    *(float4*)&Ao[r][l0] = make_float4(n0[0] / dd, n0[1] / dd, n0[2] / dd, n0[3] / dd);
  }
  // Z output: sub==7 has full K staged
  if (sub == 7 && tid < DD) {
    int i = tid;
    float a = zeff[i];
    for (int t = 0; t < CLEN; t++) {
      a += KsT[i][t];
      a = fminf(fmaxf(a, -CLAMPV), CLAMPV);
      __builtin_nontemporal_store(a, &Zout[(size_t)(b * TT + c * CLEN + t) * DD + i]);
    }
  }
  __syncthreads();
  // FFN layer 1
  {
    float a1[4] = {};
#pragma unroll 8
    for (int k = 0; k < DD; k++) {
      float4 w = *(const float4*)&W1[k * DD + l0];
      float a = Ao[r][k];
      a1[0] += a * w.x; a1[1] += a * w.y; a1[2] += a * w.z; a1[3] += a * w.w;
    }
    float4 bv = *(const float4*)&b1[l0];
    float4 h;
    h.x = fmaxf(a1[0] + bv.x, 0.f);
    h.y = fmaxf(a1[1] + bv.y, 0.f);
    h.z = fmaxf(a1[2] + bv.z, 0.f);
    h.w = fmaxf(a1[3] + bv.w, 0.f);
    *(float4*)&H1[r][l0] = h;
  }
  __syncthreads();
  // FFN layer 2 + residual
  {
    float a2[4] = {};
#pragma unroll 8
    for (int k = 0; k < DD; k++) {
      float4 w = *(const float4*)&W2[k * DD + l0];
      float a = H1[r][k];
      a2[0] += a * w.x; a2[1] += a * w.y; a2[2] += a * w.z; a2[3] += a * w.w;
    }
    int grow = b * TT + c * CLEN + t0 + r;
    float4 b2v = *(const float4*)&b2[l0];
    float4 rv = *(const float4*)&Rb[grow * DD + l0];
    float4 o;
    o.x = fmaxf(a2[0] + b2v.x, 0.f) + rv.x;
    o.y = fmaxf(a2[1] + b2v.y, 0.f) + rv.y;
    o.z = fmaxf(a2[2] + b2v.z, 0.f) + rv.z;
    o.w = fmaxf(a2[3] + b2v.w, 0.f) + rv.w;
    *(float4*)&out_main[grow * DD + l0] = o;
  }
}

extern "C" void kernel_launch(void* const* d_in, const int* in_sizes, int n_in,
                              void* d_out, int out_size, void* d_ws, size_t ws_size,
                              hipStream_t stream)
{
  const float* x     = (const float*)d_in[0];
  const float* S0    = (const float*)d_in[1];
  const float* Z0    = (const float*)d_in[2];
  const float* gamma = (const float*)d_in[3];
  const float* beta  = (const float*)d_in[4];
  const float* Wk    = (const float*)d_in[5];
  const float* Wq    = (const float*)d_in[6];
  const float* Wv    = (const float*)d_in[7];
  const float* W1    = (const float*)d_in[8];
  const float* b1    = (const float*)d_in[9];
  const float* W2    = (const float*)d_in[10];
  const float* b2    = (const float*)d_in[11];
  const float* Ws    = (const float*)d_in[12];
  const float* bs    = (const float*)d_in[13];

  float* out_main = (float*)d_out;                       // [B,T,D]
  float* Sout = out_main + NROW * DD;                    // [B,T,D*D]
  float* Zout = Sout + (size_t)NROW * DD * DD;           // [B,T,D]

  float* ws_f   = (float*)d_ws;
  float* Kb     = ws_f;                  // 524288
  float* Qb     = Kb + 524288;           // 524288
  float* Vb     = Qb + 524288;           // 524288
  float* Rb     = Vb + 524288;           // 524288  (xn@Ws + bs)
  float* prefS  = Rb + 524288;           // 1048576 (exclusive prefix + S0)
  float* prefz  = prefS + 1048576;       // 8192    (exclusive prefix + Z0)

  gemm_qkvs<<<dim3(8, 64), 256, 0, stream>>>(x, gamma, beta, Wk, Wq, Wv, Ws, bs,
                                             Kb, Qb, Vb, Rb);
  prefix_kernel<<<dim3(2, 16, BB), 256, 0, stream>>>(Kb, Vb, S0, Z0, prefS, prefz, Sout);
  attn_kernel<<<dim3(8, NCH, BB), 256, 0, stream>>>(Kb, Qb, Vb, prefS, prefz, Rb,
                                                    W1, b1, W2, b2, Zout, out_main);
}